// Round 2
// baseline (452.488 us; speedup 1.0000x reference)
//
#include <hip/hip_runtime.h>

// Problem constants (match reference)
#define ROWS        16384      // B*S = 4*4096
#define N           4096       // IN_FEATURES == OUT_FEATURES
#define COLS4       1024       // N/4 float4 chunks per row
#define NFACT       12
#define NPAIRS      2048       // N/2
#define ROWS_PER_BLOCK 64

// Key algebraic observation: the reference reshapes to [M, N/2, 2] at EVERY
// scan step (no stride doubling), so all 12 factor applications act on the
// same disjoint (2n, 2n+1) column pairs. The whole scan collapses to one
// per-pair combined 2x2 matrix:  v_out[pair n] = v_in[pair n] @ (f0..f11)[n] * alpha.
//
// Each thread owns one float4 column chunk (= 2 adjacent pairs).
// Prologue: fold the 12 per-pair 2x2 factor matrices (and alpha) into two
// combined 2x2 matrices in registers (384 B of L2-resident factor reads).
// Main loop: stream ROWS_PER_BLOCK rows with float4 loads/stores.
__global__ __launch_bounds__(256) void butterfly_fused_kernel(
    const float4* __restrict__ x,        // [ROWS][COLS4]
    const float4* __restrict__ factors,  // [NFACT][NPAIRS] of (F00,F01,F10,F11)
    const float*  __restrict__ alpha,    // [1]
    float4* __restrict__ out)            // [ROWS][COLS4]
{
    const int c  = blockIdx.x * blockDim.x + threadIdx.x;   // 0..COLS4-1
    const int r0 = blockIdx.y * ROWS_PER_BLOCK;
    const int p0 = 2 * c;
    const int p1 = 2 * c + 1;

    // Combined matrices C = f0 @ f1 @ ... @ f11 (row-vector convention:
    // v_out = v_in @ C). Start at identity.
    float a00 = 1.f, a01 = 0.f, a10 = 0.f, a11 = 1.f;   // pair p0
    float b00 = 1.f, b01 = 0.f, b10 = 0.f, b11 = 1.f;   // pair p1

#pragma unroll
    for (int f = 0; f < NFACT; ++f) {
        // factors[f][p] = (F00, F01, F10, F11), contiguous float4
        float4 F0 = factors[f * NPAIRS + p0];
        float4 F1 = factors[f * NPAIRS + p1];

        // C_new = C @ F
        float n00 = a00 * F0.x + a01 * F0.z;
        float n01 = a00 * F0.y + a01 * F0.w;
        float n10 = a10 * F0.x + a11 * F0.z;
        float n11 = a10 * F0.y + a11 * F0.w;
        a00 = n00; a01 = n01; a10 = n10; a11 = n11;

        float m00 = b00 * F1.x + b01 * F1.z;
        float m01 = b00 * F1.y + b01 * F1.w;
        float m10 = b10 * F1.x + b11 * F1.z;
        float m11 = b10 * F1.y + b11 * F1.w;
        b00 = m00; b01 = m01; b10 = m10; b11 = m11;
    }

    const float al = alpha[0];
    a00 *= al; a01 *= al; a10 *= al; a11 *= al;
    b00 *= al; b01 *= al; b10 *= al; b11 *= al;

    // Stream ROWS_PER_BLOCK rows: out[2p]   = v0*C00 + v1*C10,
    //                             out[2p+1] = v0*C01 + v1*C11
#pragma unroll 8
    for (int i = 0; i < ROWS_PER_BLOCK; ++i) {
        const size_t idx = (size_t)(r0 + i) * COLS4 + c;
        float4 v = x[idx];
        float4 o;
        o.x = v.x * a00 + v.y * a10;
        o.y = v.x * a01 + v.y * a11;
        o.z = v.z * b00 + v.w * b10;
        o.w = v.z * b01 + v.w * b11;
        out[idx] = o;
    }
}

extern "C" void kernel_launch(void* const* d_in, const int* in_sizes, int n_in,
                              void* d_out, int out_size, void* d_ws, size_t ws_size,
                              hipStream_t stream) {
    const float4* x       = (const float4*)d_in[0];
    const float4* factors = (const float4*)d_in[1];
    const float*  alpha   = (const float*)d_in[2];
    float4* out           = (float4*)d_out;

    dim3 grid(COLS4 / 256, ROWS / ROWS_PER_BLOCK);   // (4, 256) = 1024 blocks
    dim3 block(256);
    butterfly_fused_kernel<<<grid, block, 0, stream>>>(x, factors, alpha, out);
}

// Round 8
// 435.874 us; speedup vs baseline: 1.0381x; 1.0381x over previous
//
#include <hip/hip_runtime.h>

// Problem constants (match reference)
#define ROWS        16384      // B*S = 4*4096
#define N           4096       // IN_FEATURES == OUT_FEATURES
#define COLS4       1024       // N/4 float4 chunks per row
#define NFACT       12
#define NPAIRS      2048       // N/2
#define RPB         16         // rows per block in the stream kernel

// Native vector type — __builtin_nontemporal_* requires ext_vector_type,
// not HIP_vector_type.
typedef float f32x4 __attribute__((ext_vector_type(4)));

// Algebraic collapse: the reference reshapes to [M, N/2, 2] at EVERY scan
// step (no stride doubling), so all 12 factor applications act on the same
// disjoint (2n, 2n+1) column pairs:
//   v_out[pair n] = v_in[pair n] @ (f0@f1@...@f11)[n] * alpha.
//
// Kernel A: fold factors+alpha into C[2048] 2x2 matrices (32 KB in d_ws).
__global__ __launch_bounds__(256) void combine_factors_kernel(
    const f32x4* __restrict__ factors,  // [NFACT][NPAIRS] of (F00,F01,F10,F11)
    const float* __restrict__ alpha,
    f32x4* __restrict__ C)              // [NPAIRS]
{
    const int p = blockIdx.x * blockDim.x + threadIdx.x;   // 0..NPAIRS-1
    float a00 = 1.f, a01 = 0.f, a10 = 0.f, a11 = 1.f;
#pragma unroll
    for (int f = 0; f < NFACT; ++f) {
        f32x4 F = factors[f * NPAIRS + p];
        float n00 = a00 * F.x + a01 * F.z;
        float n01 = a00 * F.y + a01 * F.w;
        float n10 = a10 * F.x + a11 * F.z;
        float n11 = a10 * F.y + a11 * F.w;
        a00 = n00; a01 = n01; a10 = n10; a11 = n11;
    }
    const float al = alpha[0];
    f32x4 r;
    r.x = a00 * al; r.y = a01 * al; r.z = a10 * al; r.w = a11 * al;
    C[p] = r;
}

// Kernel B: pure stream. Each thread owns one float4 column chunk
// (= 2 adjacent pairs), loads its 2 combined matrices from the L2-resident
// 32 KB table, then streams RPB rows. 4096 blocks -> 16 blocks/CU of TLP.
__global__ __launch_bounds__(256) void butterfly_stream_kernel(
    const f32x4* __restrict__ x,    // [ROWS][COLS4]
    const f32x4* __restrict__ C,    // [NPAIRS]
    f32x4* __restrict__ out)        // [ROWS][COLS4]
{
    const int c  = blockIdx.x * blockDim.x + threadIdx.x;   // 0..COLS4-1
    const int r0 = blockIdx.y * RPB;

    const f32x4 A  = C[2 * c];
    const f32x4 Bm = C[2 * c + 1];

#pragma unroll
    for (int i = 0; i < RPB; ++i) {
        const size_t idx = (size_t)(r0 + i) * COLS4 + c;
        f32x4 v = __builtin_nontemporal_load(&x[idx]);
        f32x4 o;
        o.x = v.x * A.x  + v.y * A.z;
        o.y = v.x * A.y  + v.y * A.w;
        o.z = v.z * Bm.x + v.w * Bm.z;
        o.w = v.z * Bm.y + v.w * Bm.w;
        __builtin_nontemporal_store(o, &out[idx]);
    }
}

extern "C" void kernel_launch(void* const* d_in, const int* in_sizes, int n_in,
                              void* d_out, int out_size, void* d_ws, size_t ws_size,
                              hipStream_t stream) {
    const f32x4* x       = (const f32x4*)d_in[0];
    const f32x4* factors = (const f32x4*)d_in[1];
    const float* alpha   = (const float*)d_in[2];
    f32x4* out           = (f32x4*)d_out;
    f32x4* C             = (f32x4*)d_ws;   // 32 KB of the workspace

    combine_factors_kernel<<<NPAIRS / 256, 256, 0, stream>>>(factors, alpha, C);

    dim3 grid(COLS4 / 256, ROWS / RPB);   // (4, 1024) = 4096 blocks
    butterfly_stream_kernel<<<grid, 256, 0, stream>>>(x, C, out);
}